// Round 3
// baseline (252.693 us; speedup 1.0000x reference)
//
#include <hip/hip_runtime.h>
#include <hip/hip_bf16.h>
#include <stdint.h>

typedef unsigned short u16;
typedef short short8 __attribute__((ext_vector_type(8)));
typedef short short4v __attribute__((ext_vector_type(4)));
typedef float floatx4 __attribute__((ext_vector_type(4)));

__device__ __forceinline__ u16 f2b(float f) {
  union { float f; unsigned int u; } c; c.f = f;
  unsigned int u = c.u;
  return (u16)((u + 0x7fffu + ((u >> 16) & 1u)) >> 16);  // RNE
}

// async global->LDS, 16B per lane. LDS dest must be wave-uniform base + lane*16.
__device__ __forceinline__ void gld_lds16(const u16* g, u16* l) {
  __builtin_amdgcn_global_load_lds(
      (const __attribute__((address_space(1))) unsigned int*)g,
      (__attribute__((address_space(3))) unsigned int*)l,
      16, 0, 0);
}

// ---------------------------------------------------------------------------
// fp32 -> bf16 elementwise convert (for x). 4 elements/thread.
// ---------------------------------------------------------------------------
__global__ __launch_bounds__(256) void cvt_f2b(
    const float* __restrict__ in, u16* __restrict__ out, int n)
{
  int i = (blockIdx.x * 256 + threadIdx.x) * 4;
  if (i + 3 < n) {
    float4 f = *(const float4*)(in + i);
    short4v v;
    v[0] = (short)f2b(f.x); v[1] = (short)f2b(f.y);
    v[2] = (short)f2b(f.z); v[3] = (short)f2b(f.w);
    *(short4v*)(out + i) = v;
  }
}

// ---------------------------------------------------------------------------
// 64x64-tile transpose + fp32->bf16: out[c][r] = bf16(in[r][c]).
// ---------------------------------------------------------------------------
__global__ __launch_bounds__(256) void transpose64_f2b(
    const float* __restrict__ in, u16* __restrict__ out, int inRS, int outRS)
{
  __shared__ __align__(16) u16 t[64][72];
  const int rb = blockIdx.y * 64, cb = blockIdx.x * 64;
  const int tid = threadIdx.x;
  const int r = tid >> 2, sg = tid & 3;
  const float* ip = in + (long)(rb + r) * inRS + cb + sg * 16;
#pragma unroll
  for (int i = 0; i < 16; i += 4) {
    float4 f = *(const float4*)(ip + i);
    t[r][sg * 16 + i]     = f2b(f.x);
    t[r][sg * 16 + i + 1] = f2b(f.y);
    t[r][sg * 16 + i + 2] = f2b(f.z);
    t[r][sg * 16 + i + 3] = f2b(f.w);
  }
  __syncthreads();
  short8 v0, v1;
#pragma unroll
  for (int i = 0; i < 8; i++) v0[i] = (short)t[sg * 16 + i][r];
#pragma unroll
  for (int i = 0; i < 8; i++) v1[i] = (short)t[sg * 16 + 8 + i][r];
  *(short8*)(out + (long)(cb + r) * outRS + rb + sg * 16)     = v0;
  *(short8*)(out + (long)(cb + r) * outRS + rb + sg * 16 + 8) = v1;
}

// ---------------------------------------------------------------------------
// C[M][N] = A[M][K] * Bt[N][K]^T + bias[N]   (A,Bt bf16, fp32 accum)
// OT = u16 (bf16 out) or float (fp32 out). bias is fp32.
// 128x128 block tile, BK=32, 256 threads = 4 waves of 64x64.
// ---------------------------------------------------------------------------
__device__ __forceinline__ void store_out(u16* p, float v)  { *p = f2b(v); }
__device__ __forceinline__ void store_out(float* p, float v) { *p = v; }

template <typename OT>
__global__ __launch_bounds__(256) void gemm_bt_bias(
    const u16* __restrict__ A, const u16* __restrict__ Bt,
    const float* __restrict__ bias, OT* __restrict__ C,
    int M, int N, int K)
{
  __shared__ __align__(16) u16 sA[128 * 32];
  __shared__ __align__(16) u16 sB[128 * 32];
  const int tid = threadIdx.x;
  const int lane = tid & 63;
  const int wave = tid >> 6;
  const int wm = (wave >> 1) * 64;
  const int wn = (wave & 1) * 64;
  const int l15 = lane & 15;
  const int q = lane >> 4;
  const long rowbase = (long)blockIdx.y * 128;
  const long colbase = (long)blockIdx.x * 128;

  floatx4 acc[4][4];
#pragma unroll
  for (int i = 0; i < 4; i++)
#pragma unroll
    for (int j = 0; j < 4; j++) acc[i][j] = (floatx4){0.f, 0.f, 0.f, 0.f};

  const int c0 = tid, c1 = tid + 256;
  const int ar0 = c0 >> 2, ak0 = (c0 & 3) * 8;
  const int ar1 = c1 >> 2, ak1 = (c1 & 3) * 8;

  for (int k0 = 0; k0 < K; k0 += 32) {
    __syncthreads();
    gld_lds16(A + (rowbase + ar0) * K + k0 + ak0, sA + c0 * 8);
    gld_lds16(A + (rowbase + ar1) * K + k0 + ak1, sA + c1 * 8);
    gld_lds16(Bt + (colbase + ar0) * K + k0 + ak0, sB + c0 * 8);
    gld_lds16(Bt + (colbase + ar1) * K + k0 + ak1, sB + c1 * 8);
    __syncthreads();
    short8 af[4], bf[4];
#pragma unroll
    for (int mt = 0; mt < 4; mt++)
      af[mt] = *(const short8*)(sA + (wm + mt * 16 + l15) * 32 + q * 8);
#pragma unroll
    for (int nt = 0; nt < 4; nt++)
      bf[nt] = *(const short8*)(sB + (wn + nt * 16 + l15) * 32 + q * 8);
#pragma unroll
    for (int mt = 0; mt < 4; mt++)
#pragma unroll
      for (int nt = 0; nt < 4; nt++)
        acc[mt][nt] = __builtin_amdgcn_mfma_f32_16x16x32_bf16(af[mt], bf[nt], acc[mt][nt], 0, 0, 0);
  }

#pragma unroll
  for (int nt = 0; nt < 4; nt++) {
    const long col = colbase + wn + nt * 16 + l15;
    const float bv = bias[col];
#pragma unroll
    for (int mt = 0; mt < 4; mt++)
#pragma unroll
      for (int r = 0; r < 4; r++) {
        const long row = rowbase + wm + mt * 16 + q * 4 + r;
        store_out(C + row * N + col, acc[mt][nt][r] + bv);
      }
  }
}

// ---------------------------------------------------------------------------
// Flash attention, causal. One block = (b*12+h, q-tile of 64 rows), 256 thr.
// qkv: [8192][2304] bf16 (Q|K|V), y: [8192][768] bf16
// V tiles transposed in-LDS (staged through sP which is free then).
// ---------------------------------------------------------------------------
__global__ __launch_bounds__(256) void attn_fwd(
    const u16* __restrict__ qkv, u16* __restrict__ y)
{
  const int bh = blockIdx.x;  // b*12 + h
  const int qt = blockIdx.y;  // 0..15
  const int b = bh / 12, h = bh % 12;
  const long rowOff = (long)b * 1024;
  const int qb = qt * 64;

  __shared__ __align__(16) u16 sQ[64 * 72];
  __shared__ __align__(16) u16 sK[64 * 72];
  __shared__ __align__(16) u16 sV[64 * 72];  // V^T tile: [d][key]
  __shared__ __align__(16) u16 sP[64 * 72];  // also raw-V staging
  __shared__ float sS[64 * 65];
  __shared__ float sM[64], sL[64], sAl[64];

  const int tid = threadIdx.x;
  const int lane = tid & 63, wave = tid >> 6;
  const int l15 = lane & 15, q = lane >> 4;

  if (tid < 64) { sM[tid] = -1e9f; sL[tid] = 0.f; }

  {
    int c = tid;
#pragma unroll
    for (int rep = 0; rep < 2; rep++, c += 256) {
      int r = c >> 3, off = (c & 7) * 8;
      *(short8*)(sQ + r * 72 + off) =
          *(const short8*)(qkv + (rowOff + qb + r) * 2304 + h * 64 + off);
    }
  }

  floatx4 o[4];
#pragma unroll
  for (int nt = 0; nt < 4; nt++) o[nt] = (floatx4){0.f, 0.f, 0.f, 0.f};

  for (int j = 0; j <= qt; j++) {
    const int jb = j * 64;
    __syncthreads();
    {
      int c = tid;
#pragma unroll
      for (int rep = 0; rep < 2; rep++, c += 256) {
        int r = c >> 3, off = (c & 7) * 8;
        *(short8*)(sK + r * 72 + off) =
            *(const short8*)(qkv + (rowOff + jb + r) * 2304 + 768 + h * 64 + off);
        *(short8*)(sP + r * 72 + off) =   // raw V [key][d] staging
            *(const short8*)(qkv + (rowOff + jb + r) * 2304 + 1536 + h * 64 + off);
      }
    }
    __syncthreads();

    // transpose raw V (sP: [key][d]) -> sV [d][key]
    {
      int d = tid >> 2, sg = tid & 3;
#pragma unroll
      for (int i = 0; i < 16; i++)
        sV[d * 72 + sg * 16 + i] = sP[(sg * 16 + i) * 72 + d];
    }

    // S = scale * Q K^T  (wave handles rows 16w..16w+15, all 64 cols)
    floatx4 sf[4];
#pragma unroll
    for (int nt = 0; nt < 4; nt++) sf[nt] = (floatx4){0.f, 0.f, 0.f, 0.f};
#pragma unroll
    for (int kk = 0; kk < 64; kk += 32) {
      short8 a = *(const short8*)(sQ + (wave * 16 + l15) * 72 + kk + q * 8);
#pragma unroll
      for (int nt = 0; nt < 4; nt++) {
        short8 bb = *(const short8*)(sK + (nt * 16 + l15) * 72 + kk + q * 8);
        sf[nt] = __builtin_amdgcn_mfma_f32_16x16x32_bf16(a, bb, sf[nt], 0, 0, 0);
      }
    }
#pragma unroll
    for (int nt = 0; nt < 4; nt++)
#pragma unroll
      for (int r = 0; r < 4; r++) {
        int row = wave * 16 + q * 4 + r;
        int col = nt * 16 + l15;
        float v = sf[nt][r] * 0.125f;
        if (jb + col > qb + row) v = -1e9f;  // causal mask
        sS[row * 65 + col] = v;
      }
    __syncthreads();   // sS + sV visible

    // online softmax: 4 threads per row, 16 cols each
    {
      int row = tid >> 2, sg = tid & 3;
      float mo = sM[row];
      float vals[16], mx = -1e9f;
#pragma unroll
      for (int i = 0; i < 16; i++) {
        vals[i] = sS[row * 65 + sg * 16 + i];
        mx = fmaxf(mx, vals[i]);
      }
      mx = fmaxf(mx, __shfl_xor(mx, 1));
      mx = fmaxf(mx, __shfl_xor(mx, 2));
      float mn = fmaxf(mo, mx);
      float al = __expf(mo - mn);
      float s = 0.f;
#pragma unroll
      for (int i = 0; i < 16; i++) {
        float p = __expf(vals[i] - mn);
        s += p;
        sP[row * 72 + sg * 16 + i] = f2b(p);
      }
      s += __shfl_xor(s, 1);
      s += __shfl_xor(s, 2);
      if (sg == 0) { sAl[row] = al; sM[row] = mn; sL[row] = sL[row] * al + s; }
    }
    __syncthreads();

    // O = O*alpha + P V
    float alr[4];
#pragma unroll
    for (int r = 0; r < 4; r++) alr[r] = sAl[wave * 16 + q * 4 + r];
#pragma unroll
    for (int nt = 0; nt < 4; nt++)
#pragma unroll
      for (int r = 0; r < 4; r++) o[nt][r] *= alr[r];
#pragma unroll
    for (int kk = 0; kk < 64; kk += 32) {
      short8 a = *(const short8*)(sP + (wave * 16 + l15) * 72 + kk + q * 8);
#pragma unroll
      for (int nt = 0; nt < 4; nt++) {
        short8 bb = *(const short8*)(sV + (nt * 16 + l15) * 72 + kk + q * 8);
        o[nt] = __builtin_amdgcn_mfma_f32_16x16x32_bf16(a, bb, o[nt], 0, 0, 0);
      }
    }
  }

  __syncthreads();
  float li[4];
#pragma unroll
  for (int r = 0; r < 4; r++) li[r] = 1.f / sL[wave * 16 + q * 4 + r];
#pragma unroll
  for (int nt = 0; nt < 4; nt++)
#pragma unroll
    for (int r = 0; r < 4; r++) {
      int row = qb + wave * 16 + q * 4 + r;
      int col = h * 64 + nt * 16 + l15;
      y[(rowOff + row) * 768 + col] = f2b(o[nt][r] * li[r]);
    }
}

// ---------------------------------------------------------------------------
extern "C" void kernel_launch(void* const* d_in, const int* in_sizes, int n_in,
                              void* d_out, int out_size, void* d_ws, size_t ws_size,
                              hipStream_t stream) {
  const float* x      = (const float*)d_in[0];  // [8192][768] fp32
  const float* w_attn = (const float*)d_in[1];  // [768][2304] fp32
  const float* b_attn = (const float*)d_in[2];  // [2304] fp32
  const float* w_proj = (const float*)d_in[3];  // [768][768] fp32
  const float* b_proj = (const float*)d_in[4];  // [768] fp32
  float* out = (float*)d_out;                   // [8192][768] fp32

  char* ws = (char*)d_ws;
  u16* xb   = (u16*)ws; ws += (size_t)8192 * 768 * 2;    // 12.6 MB
  u16* wTa  = (u16*)ws; ws += (size_t)2304 * 768 * 2;    //  3.5 MB
  u16* wTp  = (u16*)ws; ws += (size_t)768 * 768 * 2;     //  1.2 MB
  u16* qkv  = (u16*)ws; ws += (size_t)8192 * 2304 * 2;   // 37.7 MB
  u16* yatt = (u16*)ws; ws += (size_t)8192 * 768 * 2;    // 12.6 MB

  // x -> bf16
  cvt_f2b<<<dim3(6144), 256, 0, stream>>>(x, xb, 8192 * 768);

  // weight transposes + bf16 convert (B^T operands for the NT GEMMs)
  transpose64_f2b<<<dim3(36, 12), 256, 0, stream>>>(w_attn, wTa, 2304, 768);
  transpose64_f2b<<<dim3(12, 12), 256, 0, stream>>>(w_proj, wTp, 768, 768);

  // qkv = x @ w_attn + b_attn   (bf16 out)
  gemm_bt_bias<u16><<<dim3(18, 64), 256, 0, stream>>>(xb, wTa, b_attn, qkv, 8192, 2304, 768);

  // flash attention (V transposed in-LDS)
  attn_fwd<<<dim3(96, 16), 256, 0, stream>>>(qkv, yatt);

  // out = yatt @ w_proj + b_proj   (fp32 out)
  gemm_bt_bias<float><<<dim3(6, 64), 256, 0, stream>>>(yatt, wTp, b_proj, out, 8192, 768, 768);
}

// Round 4
// 228.664 us; speedup vs baseline: 1.1051x; 1.1051x over previous
//
#include <hip/hip_runtime.h>
#include <hip/hip_bf16.h>
#include <stdint.h>

typedef unsigned short u16;
typedef short short8 __attribute__((ext_vector_type(8)));
typedef short short4v __attribute__((ext_vector_type(4)));
typedef float floatx4 __attribute__((ext_vector_type(4)));

__device__ __forceinline__ float b2f(u16 v) {
  union { unsigned int u; float f; } c; c.u = ((unsigned int)v) << 16; return c.f;
}
__device__ __forceinline__ u16 f2b(float f) {
  union { float f; unsigned int u; } c; c.f = f;
  unsigned int u = c.u;
  return (u16)((u + 0x7fffu + ((u >> 16) & 1u)) >> 16);  // RNE
}

// async global->LDS, 16B per lane. LDS dest must be wave-uniform base + lane*16.
__device__ __forceinline__ void gld_lds16(const u16* g, u16* l) {
  __builtin_amdgcn_global_load_lds(
      (const __attribute__((address_space(1))) unsigned int*)g,
      (__attribute__((address_space(3))) unsigned int*)l,
      16, 0, 0);
}

// ---------------------------------------------------------------------------
// fp32 -> bf16 elementwise convert (for x). 4 elements/thread.
// ---------------------------------------------------------------------------
__global__ __launch_bounds__(256) void cvt_f2b(
    const float* __restrict__ in, u16* __restrict__ out, int n)
{
  int i = (blockIdx.x * 256 + threadIdx.x) * 4;
  if (i + 3 < n) {
    float4 f = *(const float4*)(in + i);
    short4v v;
    v[0] = (short)f2b(f.x); v[1] = (short)f2b(f.y);
    v[2] = (short)f2b(f.z); v[3] = (short)f2b(f.w);
    *(short4v*)(out + i) = v;
  }
}

// ---------------------------------------------------------------------------
// 64x64-tile transpose + fp32->bf16: out[c][r] = bf16(in[r][c]).
// ---------------------------------------------------------------------------
__global__ __launch_bounds__(256) void transpose64_f2b(
    const float* __restrict__ in, u16* __restrict__ out, int inRS, int outRS)
{
  __shared__ __align__(16) u16 t[64][72];
  const int rb = blockIdx.y * 64, cb = blockIdx.x * 64;
  const int tid = threadIdx.x;
  const int r = tid >> 2, sg = tid & 3;
  const float* ip = in + (long)(rb + r) * inRS + cb + sg * 16;
#pragma unroll
  for (int i = 0; i < 16; i += 4) {
    float4 f = *(const float4*)(ip + i);
    t[r][sg * 16 + i]     = f2b(f.x);
    t[r][sg * 16 + i + 1] = f2b(f.y);
    t[r][sg * 16 + i + 2] = f2b(f.z);
    t[r][sg * 16 + i + 3] = f2b(f.w);
  }
  __syncthreads();
  short8 v0, v1;
#pragma unroll
  for (int i = 0; i < 8; i++) v0[i] = (short)t[sg * 16 + i][r];
#pragma unroll
  for (int i = 0; i < 8; i++) v1[i] = (short)t[sg * 16 + 8 + i][r];
  *(short8*)(out + (long)(cb + r) * outRS + rb + sg * 16)     = v0;
  *(short8*)(out + (long)(cb + r) * outRS + rb + sg * 16 + 8) = v1;
}

// ---------------------------------------------------------------------------
// C[M][N] = A[M][K] * Bt[N][K]^T + bias[N]   (A,Bt bf16, fp32 accum)
// OT = u16 (bf16 out) or float (fp32 out). bias is fp32.
// 128x128 block tile, BK=32, 256 threads = 4 waves of 64x64.
// ---------------------------------------------------------------------------
__device__ __forceinline__ void store_out(u16* p, float v)  { *p = f2b(v); }
__device__ __forceinline__ void store_out(float* p, float v) { *p = v; }

template <typename OT>
__global__ __launch_bounds__(256) void gemm_bt_bias(
    const u16* __restrict__ A, const u16* __restrict__ Bt,
    const float* __restrict__ bias, OT* __restrict__ C,
    int M, int N, int K)
{
  __shared__ __align__(16) u16 sA[128 * 32];
  __shared__ __align__(16) u16 sB[128 * 32];
  const int tid = threadIdx.x;
  const int lane = tid & 63;
  const int wave = tid >> 6;
  const int wm = (wave >> 1) * 64;
  const int wn = (wave & 1) * 64;
  const int l15 = lane & 15;
  const int q = lane >> 4;
  const long rowbase = (long)blockIdx.y * 128;
  const long colbase = (long)blockIdx.x * 128;

  floatx4 acc[4][4];
#pragma unroll
  for (int i = 0; i < 4; i++)
#pragma unroll
    for (int j = 0; j < 4; j++) acc[i][j] = (floatx4){0.f, 0.f, 0.f, 0.f};

  const int c0 = tid, c1 = tid + 256;
  const int ar0 = c0 >> 2, ak0 = (c0 & 3) * 8;
  const int ar1 = c1 >> 2, ak1 = (c1 & 3) * 8;

  for (int k0 = 0; k0 < K; k0 += 32) {
    __syncthreads();
    gld_lds16(A + (rowbase + ar0) * K + k0 + ak0, sA + c0 * 8);
    gld_lds16(A + (rowbase + ar1) * K + k0 + ak1, sA + c1 * 8);
    gld_lds16(Bt + (colbase + ar0) * K + k0 + ak0, sB + c0 * 8);
    gld_lds16(Bt + (colbase + ar1) * K + k0 + ak1, sB + c1 * 8);
    __syncthreads();
    short8 af[4], bf[4];
#pragma unroll
    for (int mt = 0; mt < 4; mt++)
      af[mt] = *(const short8*)(sA + (wm + mt * 16 + l15) * 32 + q * 8);
#pragma unroll
    for (int nt = 0; nt < 4; nt++)
      bf[nt] = *(const short8*)(sB + (wn + nt * 16 + l15) * 32 + q * 8);
#pragma unroll
    for (int mt = 0; mt < 4; mt++)
#pragma unroll
      for (int nt = 0; nt < 4; nt++)
        acc[mt][nt] = __builtin_amdgcn_mfma_f32_16x16x32_bf16(af[mt], bf[nt], acc[mt][nt], 0, 0, 0);
  }

#pragma unroll
  for (int nt = 0; nt < 4; nt++) {
    const long col = colbase + wn + nt * 16 + l15;
    const float bv = bias[col];
#pragma unroll
    for (int mt = 0; mt < 4; mt++)
#pragma unroll
      for (int r = 0; r < 4; r++) {
        const long row = rowbase + wm + mt * 16 + q * 4 + r;
        store_out(C + row * N + col, acc[mt][nt][r] + bv);
      }
  }
}

// ---------------------------------------------------------------------------
// Flash attention, causal. One block = (b*12+h, q-tile of 64 rows), 256 thr.
// S^T = K (Q/8)^T formulation: softmax rows live on lane&15 -> in-register
// online softmax (shfl_xor 16/32), no S round-trip, 2 barriers/iter.
// qkv: [8192][2304] bf16 (Q|K|V), y: [8192][768] bf16
// ---------------------------------------------------------------------------
__global__ __launch_bounds__(256) void attn_fwd(
    const u16* __restrict__ qkv, u16* __restrict__ y)
{
  const int bh = blockIdx.x;        // b*12 + h
  const int qt = 15 - blockIdx.y;   // reversed: long blocks dispatch first
  const int b = bh / 12, h = bh % 12;
  const long rowOff = (long)b * 1024;
  const int qb = qt * 64;

  __shared__ __align__(16) u16 sK[64 * 72];
  __shared__ __align__(16) u16 sVs[64 * 72];  // raw V staging [key][d]
  __shared__ __align__(16) u16 sV[64 * 72];   // V^T [d][key]
  __shared__ __align__(16) u16 sP[64 * 72];   // P [qrow][key]

  const int tid = threadIdx.x;
  const int lane = tid & 63, wave = tid >> 6;
  const int l15 = lane & 15, q = lane >> 4;
  const int qrow_g = qb + wave * 16 + l15;    // this lane's softmax row

  // Q fragments in registers, pre-scaled by 1/8 (B-operand: n=l15, k=q*8+j)
  short8 qf[2];
  {
    const u16* qp = qkv + (long)(rowOff + qrow_g) * 2304 + h * 64 + q * 8;
    short8 a0 = *(const short8*)(qp);
    short8 a1 = *(const short8*)(qp + 32);
#pragma unroll
    for (int i = 0; i < 8; i++) {
      a0[i] = (short)f2b(b2f((u16)a0[i]) * 0.125f);
      a1[i] = (short)f2b(b2f((u16)a1[i]) * 0.125f);
    }
    qf[0] = a0; qf[1] = a1;
  }

  float m_i = -1e30f, l_i = 0.f;
  floatx4 o[4];
#pragma unroll
  for (int nt = 0; nt < 4; nt++) o[nt] = (floatx4){0.f, 0.f, 0.f, 0.f};

  for (int j = 0; j <= qt; j++) {
    const int jb = j * 64;
    // stage K and raw V (vector loads; padded LDS keeps frag reads 2-way)
#pragma unroll
    for (int rep = 0; rep < 2; rep++) {
      int idx = tid + rep * 256;
      int r = idx >> 3, ch = (idx & 7) * 8;
      const u16* src = qkv + (long)(rowOff + jb + r) * 2304 + 768 + h * 64 + ch;
      *(short8*)(sK + r * 72 + ch)  = *(const short8*)(src);
      *(short8*)(sVs + r * 72 + ch) = *(const short8*)(src + 768);
    }
    __syncthreads();

    // transpose V: sVs[key][d] -> sV[d][key], packed b64 writes
    {
      int d = tid >> 2, kg = (tid & 3) * 16;
      u16 tmp[16];
#pragma unroll
      for (int i = 0; i < 16; i++) tmp[i] = sVs[(kg + i) * 72 + d];
#pragma unroll
      for (int s = 0; s < 4; s++) {
        short4v vv;
        vv[0] = (short)tmp[s*4]; vv[1] = (short)tmp[s*4+1];
        vv[2] = (short)tmp[s*4+2]; vv[3] = (short)tmp[s*4+3];
        *(short4v*)(sV + d * 72 + kg + s * 4) = vv;
      }
    }

    // S^T = K (Q/8)^T : fragments mt over 16-key blocks
    floatx4 sf[4];
#pragma unroll
    for (int mt = 0; mt < 4; mt++) sf[mt] = (floatx4){0.f, 0.f, 0.f, 0.f};
#pragma unroll
    for (int kk = 0; kk < 2; kk++) {
#pragma unroll
      for (int mt = 0; mt < 4; mt++) {
        short8 kf = *(const short8*)(sK + (mt * 16 + l15) * 72 + kk * 32 + q * 8);
        sf[mt] = __builtin_amdgcn_mfma_f32_16x16x32_bf16(kf, qf[kk], sf[mt], 0, 0, 0);
      }
    }

    // causal mask + in-register online softmax (row = l15-qrow)
    float mx = m_i;
#pragma unroll
    for (int mt = 0; mt < 4; mt++)
#pragma unroll
      for (int r = 0; r < 4; r++) {
        int key_g = jb + mt * 16 + q * 4 + r;
        float v = sf[mt][r];
        if (key_g > qrow_g) v = -1e30f;
        sf[mt][r] = v;
        mx = fmaxf(mx, v);
      }
    mx = fmaxf(mx, __shfl_xor(mx, 16));
    mx = fmaxf(mx, __shfl_xor(mx, 32));
    float al = __expf(m_i - mx);
    m_i = mx;
    float rsum = 0.f;
#pragma unroll
    for (int mt = 0; mt < 4; mt++) {
      short4v pv;
#pragma unroll
      for (int r = 0; r < 4; r++) {
        float p = __expf(sf[mt][r] - mx);
        rsum += p;
        pv[r] = (short)f2b(p);
      }
      *(short4v*)(sP + (wave * 16 + l15) * 72 + mt * 16 + q * 4) = pv;
    }
    rsum += __shfl_xor(rsum, 16);
    rsum += __shfl_xor(rsum, 32);
    l_i = l_i * al + rsum;
    __syncthreads();   // sV + sP visible before PV

    // O = O*alpha + P V   (o rows are q*4+r -> fetch alpha from lane q*4+r)
    float al_r[4];
#pragma unroll
    for (int r = 0; r < 4; r++) al_r[r] = __shfl(al, q * 4 + r);
#pragma unroll
    for (int nt = 0; nt < 4; nt++)
#pragma unroll
      for (int r = 0; r < 4; r++) o[nt][r] *= al_r[r];
#pragma unroll
    for (int kk = 0; kk < 2; kk++) {
      short8 pf = *(const short8*)(sP + (wave * 16 + l15) * 72 + kk * 32 + q * 8);
#pragma unroll
      for (int nt = 0; nt < 4; nt++) {
        short8 vf = *(const short8*)(sV + (nt * 16 + l15) * 72 + kk * 32 + q * 8);
        o[nt] = __builtin_amdgcn_mfma_f32_16x16x32_bf16(pf, vf, o[nt], 0, 0, 0);
      }
    }
  }

  float linv = 1.f / l_i;
  float li_r[4];
#pragma unroll
  for (int r = 0; r < 4; r++) li_r[r] = __shfl(linv, q * 4 + r);
#pragma unroll
  for (int nt = 0; nt < 4; nt++)
#pragma unroll
    for (int r = 0; r < 4; r++) {
      int row = qb + wave * 16 + q * 4 + r;
      int col = h * 64 + nt * 16 + l15;
      y[(rowOff + row) * 768 + col] = f2b(o[nt][r] * li_r[r]);
    }
}

// ---------------------------------------------------------------------------
extern "C" void kernel_launch(void* const* d_in, const int* in_sizes, int n_in,
                              void* d_out, int out_size, void* d_ws, size_t ws_size,
                              hipStream_t stream) {
  const float* x      = (const float*)d_in[0];  // [8192][768] fp32
  const float* w_attn = (const float*)d_in[1];  // [768][2304] fp32
  const float* b_attn = (const float*)d_in[2];  // [2304] fp32
  const float* w_proj = (const float*)d_in[3];  // [768][768] fp32
  const float* b_proj = (const float*)d_in[4];  // [768] fp32
  float* out = (float*)d_out;                   // [8192][768] fp32

  char* ws = (char*)d_ws;
  u16* xb   = (u16*)ws; ws += (size_t)8192 * 768 * 2;    // 12.6 MB
  u16* wTa  = (u16*)ws; ws += (size_t)2304 * 768 * 2;    //  3.5 MB
  u16* wTp  = (u16*)ws; ws += (size_t)768 * 768 * 2;     //  1.2 MB
  u16* qkv  = (u16*)ws; ws += (size_t)8192 * 2304 * 2;   // 37.7 MB
  u16* yatt = (u16*)ws; ws += (size_t)8192 * 768 * 2;    // 12.6 MB

  // x -> bf16
  cvt_f2b<<<dim3(6144), 256, 0, stream>>>(x, xb, 8192 * 768);

  // weight transposes + bf16 convert (B^T operands for the NT GEMMs)
  transpose64_f2b<<<dim3(36, 12), 256, 0, stream>>>(w_attn, wTa, 2304, 768);
  transpose64_f2b<<<dim3(12, 12), 256, 0, stream>>>(w_proj, wTp, 768, 768);

  // qkv = x @ w_attn + b_attn   (bf16 out)
  gemm_bt_bias<u16><<<dim3(18, 64), 256, 0, stream>>>(xb, wTa, b_attn, qkv, 8192, 2304, 768);

  // flash attention (in-register softmax)
  attn_fwd<<<dim3(96, 16), 256, 0, stream>>>(qkv, yatt);

  // out = yatt @ w_proj + b_proj   (fp32 out)
  gemm_bt_bias<float><<<dim3(6, 64), 256, 0, stream>>>(yatt, wTp, b_proj, out, 8192, 768, 768);
}

// Round 5
// 221.822 us; speedup vs baseline: 1.1392x; 1.0308x over previous
//
#include <hip/hip_runtime.h>
#include <hip/hip_bf16.h>
#include <stdint.h>

typedef unsigned short u16;
typedef short short8 __attribute__((ext_vector_type(8)));
typedef short short4v __attribute__((ext_vector_type(4)));
typedef float floatx4 __attribute__((ext_vector_type(4)));

__device__ __forceinline__ float b2f(u16 v) {
  union { unsigned int u; float f; } c; c.u = ((unsigned int)v) << 16; return c.f;
}
__device__ __forceinline__ u16 f2b(float f) {
  union { float f; unsigned int u; } c; c.f = f;
  unsigned int u = c.u;
  return (u16)((u + 0x7fffu + ((u >> 16) & 1u)) >> 16);  // RNE
}

// async global->LDS, 16B per lane. LDS dest must be wave-uniform base + lane*16.
__device__ __forceinline__ void gld_lds16(const u16* g, u16* l) {
  __builtin_amdgcn_global_load_lds(
      (const __attribute__((address_space(1))) unsigned int*)g,
      (__attribute__((address_space(3))) unsigned int*)l,
      16, 0, 0);
}

// ---------------------------------------------------------------------------
// Fused prep: x fp32->bf16 (blocks 0..6143), w_attn T (6144..6575),
// w_proj T (6576..6719). Transposes also convert fp32->bf16.
// ---------------------------------------------------------------------------
__device__ __forceinline__ void tile_transpose_f2b(
    const float* __restrict__ in, u16* __restrict__ out,
    int inRS, int outRS, int rb, int cb, int tid)
{
  __shared__ __align__(16) u16 t[64][72];
  const int r = tid >> 2, sg = tid & 3;
  const float* ip = in + (long)(rb + r) * inRS + cb + sg * 16;
#pragma unroll
  for (int i = 0; i < 16; i += 4) {
    float4 f = *(const float4*)(ip + i);
    t[r][sg * 16 + i]     = f2b(f.x);
    t[r][sg * 16 + i + 1] = f2b(f.y);
    t[r][sg * 16 + i + 2] = f2b(f.z);
    t[r][sg * 16 + i + 3] = f2b(f.w);
  }
  __syncthreads();
  short8 v0, v1;
#pragma unroll
  for (int i = 0; i < 8; i++) v0[i] = (short)t[sg * 16 + i][r];
#pragma unroll
  for (int i = 0; i < 8; i++) v1[i] = (short)t[sg * 16 + 8 + i][r];
  *(short8*)(out + (long)(cb + r) * outRS + rb + sg * 16)     = v0;
  *(short8*)(out + (long)(cb + r) * outRS + rb + sg * 16 + 8) = v1;
}

__global__ __launch_bounds__(256) void prep(
    const float* __restrict__ x, u16* __restrict__ xb,
    const float* __restrict__ w_attn, u16* __restrict__ wTa,
    const float* __restrict__ w_proj, u16* __restrict__ wTp)
{
  const int bid = blockIdx.x, tid = threadIdx.x;
  if (bid < 6144) {
    int i = (bid * 256 + tid) * 4;
    float4 f = *(const float4*)(x + i);
    short4v v;
    v[0] = (short)f2b(f.x); v[1] = (short)f2b(f.y);
    v[2] = (short)f2b(f.z); v[3] = (short)f2b(f.w);
    *(short4v*)(xb + i) = v;
  } else if (bid < 6576) {
    int t = bid - 6144;                 // 36 x 12 tiles of w_attn [768][2304]
    tile_transpose_f2b(w_attn, wTa, 2304, 768, (t / 36) * 64, (t % 36) * 64, tid);
  } else {
    int t = bid - 6576;                 // 12 x 12 tiles of w_proj [768][768]
    tile_transpose_f2b(w_proj, wTp, 768, 768, (t / 12) * 64, (t % 12) * 64, tid);
  }
}

// ---------------------------------------------------------------------------
// C[M][N] = A[M][K] * Bt[N][K]^T + bias[N]   (A,Bt bf16, fp32 accum)
// BM=128: 2x2 waves of 64x64. BM=64: 1x4 waves of 64x32 (BN=128 both).
// Double-buffered LDS: issue buf[i+1] -> compute buf[i] -> barrier.
// ---------------------------------------------------------------------------
__device__ __forceinline__ void store_out(u16* p, float v)  { *p = f2b(v); }
__device__ __forceinline__ void store_out(float* p, float v) { *p = v; }

template <int BM>
__device__ __forceinline__ void stage(
    const u16* __restrict__ A, const u16* __restrict__ Bt,
    long rowbase, long colbase, int K, int k0,
    u16* dA, u16* dB, int tid)
{
  const int c0 = tid, c1 = tid + 256;
  const int ar0 = c0 >> 2, ak0 = (c0 & 3) * 8;
  const int ar1 = c1 >> 2, ak1 = (c1 & 3) * 8;
  gld_lds16(A + (rowbase + ar0) * K + k0 + ak0, dA + c0 * 8);
  if (BM == 128)
    gld_lds16(A + (rowbase + ar1) * K + k0 + ak1, dA + c1 * 8);
  gld_lds16(Bt + (colbase + ar0) * K + k0 + ak0, dB + c0 * 8);
  gld_lds16(Bt + (colbase + ar1) * K + k0 + ak1, dB + c1 * 8);
}

template <typename OT, int BM>
__global__ __launch_bounds__(256) void gemm_bt_bias(
    const u16* __restrict__ A, const u16* __restrict__ Bt,
    const float* __restrict__ bias, OT* __restrict__ C,
    int M, int N, int K)
{
  constexpr int WNF = (BM == 128) ? 4 : 2;      // n-frags per wave
  __shared__ __align__(16) u16 sA[2][BM * 32];
  __shared__ __align__(16) u16 sB[2][128 * 32];
  const int tid = threadIdx.x;
  const int lane = tid & 63;
  const int wave = tid >> 6;
  const int wm = (BM == 128) ? (wave >> 1) * 64 : 0;
  const int wn = (BM == 128) ? (wave & 1) * 64 : wave * 32;
  const int l15 = lane & 15;
  const int q = lane >> 4;
  const long rowbase = (long)blockIdx.y * BM;
  const long colbase = (long)blockIdx.x * 128;

  floatx4 acc[4][WNF];
#pragma unroll
  for (int i = 0; i < 4; i++)
#pragma unroll
    for (int j = 0; j < WNF; j++) acc[i][j] = (floatx4){0.f, 0.f, 0.f, 0.f};

  stage<BM>(A, Bt, rowbase, colbase, K, 0, sA[0], sB[0], tid);
  __syncthreads();   // vmcnt(0) drain: buf0 ready

  const int NIT = K / 32;
  for (int it = 0; it < NIT; ++it) {
    const int cur = it & 1;
    if (it + 1 < NIT)
      stage<BM>(A, Bt, rowbase, colbase, K, (it + 1) * 32, sA[cur ^ 1], sB[cur ^ 1], tid);
    short8 af[4], bf[WNF];
#pragma unroll
    for (int mt = 0; mt < 4; mt++)
      af[mt] = *(const short8*)(sA[cur] + (wm + mt * 16 + l15) * 32 + q * 8);
#pragma unroll
    for (int nt = 0; nt < WNF; nt++)
      bf[nt] = *(const short8*)(sB[cur] + (wn + nt * 16 + l15) * 32 + q * 8);
#pragma unroll
    for (int mt = 0; mt < 4; mt++)
#pragma unroll
      for (int nt = 0; nt < WNF; nt++)
        acc[mt][nt] = __builtin_amdgcn_mfma_f32_16x16x32_bf16(af[mt], bf[nt], acc[mt][nt], 0, 0, 0);
    if (it + 1 < NIT) __syncthreads();  // ends compute(cur); drains prefetch DMA
  }

#pragma unroll
  for (int nt = 0; nt < WNF; nt++) {
    const long col = colbase + wn + nt * 16 + l15;
    const float bv = bias[col];
#pragma unroll
    for (int mt = 0; mt < 4; mt++)
#pragma unroll
      for (int r = 0; r < 4; r++) {
        const long row = rowbase + wm + mt * 16 + q * 4 + r;
        store_out(C + row * N + col, acc[mt][nt][r] + bv);
      }
  }
}

// ---------------------------------------------------------------------------
// Flash attention, causal. One block = (b*12+h, q-tile of 64 rows), 256 thr.
// S^T = K (Q/8)^T formulation: softmax rows live on lane&15 -> in-register
// online softmax (shfl_xor 16/32), no S round-trip, 2 barriers/iter.
// qkv: [8192][2304] bf16 (Q|K|V), y: [8192][768] bf16
// ---------------------------------------------------------------------------
__global__ __launch_bounds__(256) void attn_fwd(
    const u16* __restrict__ qkv, u16* __restrict__ y)
{
  const int bh = blockIdx.x;        // b*12 + h
  const int qt = 15 - blockIdx.y;   // reversed: long blocks dispatch first
  const int b = bh / 12, h = bh % 12;
  const long rowOff = (long)b * 1024;
  const int qb = qt * 64;

  __shared__ __align__(16) u16 sK[64 * 72];
  __shared__ __align__(16) u16 sVs[64 * 72];  // raw V staging [key][d]
  __shared__ __align__(16) u16 sV[64 * 72];   // V^T [d][key]
  __shared__ __align__(16) u16 sP[64 * 72];   // P [qrow][key]

  const int tid = threadIdx.x;
  const int lane = tid & 63, wave = tid >> 6;
  const int l15 = lane & 15, q = lane >> 4;
  const int qrow_g = qb + wave * 16 + l15;    // this lane's softmax row

  // Q fragments in registers, pre-scaled by 1/8 (B-operand: n=l15, k=q*8+j)
  short8 qf[2];
  {
    const u16* qp = qkv + (long)(rowOff + qrow_g) * 2304 + h * 64 + q * 8;
    short8 a0 = *(const short8*)(qp);
    short8 a1 = *(const short8*)(qp + 32);
#pragma unroll
    for (int i = 0; i < 8; i++) {
      a0[i] = (short)f2b(b2f((u16)a0[i]) * 0.125f);
      a1[i] = (short)f2b(b2f((u16)a1[i]) * 0.125f);
    }
    qf[0] = a0; qf[1] = a1;
  }

  float m_i = -1e30f, l_i = 0.f;
  floatx4 o[4];
#pragma unroll
  for (int nt = 0; nt < 4; nt++) o[nt] = (floatx4){0.f, 0.f, 0.f, 0.f};

  for (int j = 0; j <= qt; j++) {
    const int jb = j * 64;
#pragma unroll
    for (int rep = 0; rep < 2; rep++) {
      int idx = tid + rep * 256;
      int r = idx >> 3, ch = (idx & 7) * 8;
      const u16* src = qkv + (long)(rowOff + jb + r) * 2304 + 768 + h * 64 + ch;
      *(short8*)(sK + r * 72 + ch)  = *(const short8*)(src);
      *(short8*)(sVs + r * 72 + ch) = *(const short8*)(src + 768);
    }
    __syncthreads();

    // transpose V: sVs[key][d] -> sV[d][key], packed b64 writes
    {
      int d = tid >> 2, kg = (tid & 3) * 16;
      u16 tmp[16];
#pragma unroll
      for (int i = 0; i < 16; i++) tmp[i] = sVs[(kg + i) * 72 + d];
#pragma unroll
      for (int s = 0; s < 4; s++) {
        short4v vv;
        vv[0] = (short)tmp[s*4]; vv[1] = (short)tmp[s*4+1];
        vv[2] = (short)tmp[s*4+2]; vv[3] = (short)tmp[s*4+3];
        *(short4v*)(sV + d * 72 + kg + s * 4) = vv;
      }
    }

    // S^T = K (Q/8)^T : fragments mt over 16-key blocks
    floatx4 sf[4];
#pragma unroll
    for (int mt = 0; mt < 4; mt++) sf[mt] = (floatx4){0.f, 0.f, 0.f, 0.f};
#pragma unroll
    for (int kk = 0; kk < 2; kk++) {
#pragma unroll
      for (int mt = 0; mt < 4; mt++) {
        short8 kf = *(const short8*)(sK + (mt * 16 + l15) * 72 + kk * 32 + q * 8);
        sf[mt] = __builtin_amdgcn_mfma_f32_16x16x32_bf16(kf, qf[kk], sf[mt], 0, 0, 0);
      }
    }

    // causal mask + in-register online softmax (row = l15-qrow)
    float mx = m_i;
#pragma unroll
    for (int mt = 0; mt < 4; mt++)
#pragma unroll
      for (int r = 0; r < 4; r++) {
        int key_g = jb + mt * 16 + q * 4 + r;
        float v = sf[mt][r];
        if (key_g > qrow_g) v = -1e30f;
        sf[mt][r] = v;
        mx = fmaxf(mx, v);
      }
    mx = fmaxf(mx, __shfl_xor(mx, 16));
    mx = fmaxf(mx, __shfl_xor(mx, 32));
    float al = __expf(m_i - mx);
    m_i = mx;
    float rsum = 0.f;
#pragma unroll
    for (int mt = 0; mt < 4; mt++) {
      short4v pv;
#pragma unroll
      for (int r = 0; r < 4; r++) {
        float p = __expf(sf[mt][r] - mx);
        rsum += p;
        pv[r] = (short)f2b(p);
      }
      *(short4v*)(sP + (wave * 16 + l15) * 72 + mt * 16 + q * 4) = pv;
    }
    rsum += __shfl_xor(rsum, 16);
    rsum += __shfl_xor(rsum, 32);
    l_i = l_i * al + rsum;
    __syncthreads();   // sV + sP visible before PV

    // O = O*alpha + P V   (o rows are q*4+r -> fetch alpha from lane q*4+r)
    float al_r[4];
#pragma unroll
    for (int r = 0; r < 4; r++) al_r[r] = __shfl(al, q * 4 + r);
#pragma unroll
    for (int nt = 0; nt < 4; nt++)
#pragma unroll
      for (int r = 0; r < 4; r++) o[nt][r] *= al_r[r];
#pragma unroll
    for (int kk = 0; kk < 2; kk++) {
      short8 pf = *(const short8*)(sP + (wave * 16 + l15) * 72 + kk * 32 + q * 8);
#pragma unroll
      for (int nt = 0; nt < 4; nt++) {
        short8 vf = *(const short8*)(sV + (nt * 16 + l15) * 72 + kk * 32 + q * 8);
        o[nt] = __builtin_amdgcn_mfma_f32_16x16x32_bf16(pf, vf, o[nt], 0, 0, 0);
      }
    }
  }

  float linv = 1.f / l_i;
  float li_r[4];
#pragma unroll
  for (int r = 0; r < 4; r++) li_r[r] = __shfl(linv, q * 4 + r);
#pragma unroll
  for (int nt = 0; nt < 4; nt++)
#pragma unroll
    for (int r = 0; r < 4; r++) {
      int row = qb + wave * 16 + q * 4 + r;
      int col = h * 64 + nt * 16 + l15;
      y[(rowOff + row) * 768 + col] = f2b(o[nt][r] * li_r[r]);
    }
}

// ---------------------------------------------------------------------------
extern "C" void kernel_launch(void* const* d_in, const int* in_sizes, int n_in,
                              void* d_out, int out_size, void* d_ws, size_t ws_size,
                              hipStream_t stream) {
  const float* x      = (const float*)d_in[0];  // [8192][768] fp32
  const float* w_attn = (const float*)d_in[1];  // [768][2304] fp32
  const float* b_attn = (const float*)d_in[2];  // [2304] fp32
  const float* w_proj = (const float*)d_in[3];  // [768][768] fp32
  const float* b_proj = (const float*)d_in[4];  // [768] fp32
  float* out = (float*)d_out;                   // [8192][768] fp32

  char* ws = (char*)d_ws;
  u16* xb   = (u16*)ws; ws += (size_t)8192 * 768 * 2;    // 12.6 MB
  u16* wTa  = (u16*)ws; ws += (size_t)2304 * 768 * 2;    //  3.5 MB
  u16* wTp  = (u16*)ws; ws += (size_t)768 * 768 * 2;     //  1.2 MB
  u16* qkv  = (u16*)ws; ws += (size_t)8192 * 2304 * 2;   // 37.7 MB
  u16* yatt = (u16*)ws; ws += (size_t)8192 * 768 * 2;    // 12.6 MB

  // fused prep: x->bf16 + both weight transposes
  prep<<<dim3(6720), 256, 0, stream>>>(x, xb, w_attn, wTa, w_proj, wTp);

  // qkv = x @ w_attn + b_attn   (bf16 out, 128x128 tiles)
  gemm_bt_bias<u16, 128><<<dim3(18, 64), 256, 0, stream>>>(xb, wTa, b_attn, qkv, 8192, 2304, 768);

  // flash attention (in-register softmax)
  attn_fwd<<<dim3(96, 16), 256, 0, stream>>>(qkv, yatt);

  // out = yatt @ w_proj + b_proj   (fp32 out, 64x128 tiles -> 768 blocks)
  gemm_bt_bias<float, 64><<<dim3(6, 128), 256, 0, stream>>>(yatt, wTp, b_proj, out, 8192, 768, 768);
}